// Round 1
// baseline (702.507 us; speedup 1.0000x reference)
//
#include <hip/hip_runtime.h>
#include <math.h>

// Problem constants (fixed by the reference: N=16384, H=16, C=32, NE=196608)
#define H_DIM 16
#define C_DIM 32
#define EPSF 1e-5f

__device__ __forceinline__ float reduce8(float x) {
    // sum across the 8 lanes that share one head; lanes are contiguous within
    // a 64-lane wave, so xor masks 1/2/4 never cross the wave boundary.
    x += __shfl_xor(x, 1);
    x += __shfl_xor(x, 2);
    x += __shfl_xor(x, 4);
    return x;
}

__global__ void zero_kernel(int* __restrict__ p, int n) {
    int i = blockIdx.x * blockDim.x + threadIdx.x;
    if (i < n) p[i] = 0;
}

__global__ void hist_kernel(const int* __restrict__ edst, int* __restrict__ counts, int ne) {
    int i = blockIdx.x * blockDim.x + threadIdx.x;
    if (i < ne) atomicAdd(&counts[edst[i]], 1);
}

// Single-block exclusive scan over counts[n] -> offsets[n+1]. n=16384 -> 16 chunks.
__global__ __launch_bounds__(1024)
void scan_kernel(const int* __restrict__ counts, int* __restrict__ offsets, int n) {
    __shared__ int sdata[1024];
    __shared__ int carry_s;
    const int tid = threadIdx.x;
    if (tid == 0) { carry_s = 0; offsets[0] = 0; }
    __syncthreads();
    for (int base = 0; base < n; base += 1024) {
        int x = (base + tid < n) ? counts[base + tid] : 0;
        sdata[tid] = x;
        __syncthreads();
        for (int off = 1; off < 1024; off <<= 1) {
            int val = (tid >= off) ? sdata[tid - off] : 0;
            __syncthreads();
            sdata[tid] += val;
            __syncthreads();
        }
        int inc = sdata[tid];
        int carry = carry_s;
        if (base + tid < n) offsets[base + tid + 1] = carry + inc;
        __syncthreads();
        if (tid == 1023) carry_s = carry + inc;
        __syncthreads();
    }
}

__global__ void scatter_kernel(const int* __restrict__ esrc, const int* __restrict__ edst,
                               const int* __restrict__ offsets, int* __restrict__ cursor,
                               int* __restrict__ perm_eid, int* __restrict__ perm_src, int ne) {
    int i = blockIdx.x * blockDim.x + threadIdx.x;
    if (i < ne) {
        int d = edst[i];
        int pos = offsets[d] + atomicAdd(&cursor[d], 1);
        perm_eid[pos] = i;
        perm_src[pos] = esrc[i];
    }
}

// One block per dst node. 128 threads = 16 heads x 8 lanes; each lane owns a
// float4 of the C=32 channel dim. Online (flash) softmax over incoming edges.
__global__ __launch_bounds__(128)
void attn_kernel(const float* __restrict__ q, const float* __restrict__ k,
                 const float* __restrict__ v, const float* __restrict__ e,
                 const float* __restrict__ wq, const float* __restrict__ wk,
                 const int* __restrict__ offsets, const int* __restrict__ perm_eid,
                 const int* __restrict__ perm_src, float* __restrict__ out)
{
    const int node = blockIdx.x;
    const int t = threadIdx.x;
    const int h = t >> 3;
    const int c4 = (t & 7) << 2;
    const float qk_scale = 0.17677669529663687f;  // 1/sqrt(32)

    const size_t node_off = ((size_t)node * H_DIM + h) * C_DIM + c4;

    // fused q RMSNorm (once per node)
    float4 qv = *(const float4*)(q + node_off);
    float qs = qv.x * qv.x + qv.y * qv.y + qv.z * qv.z + qv.w * qv.w;
    qs = reduce8(qs);
    float qinv = rsqrtf(qs * (1.0f / C_DIM) + EPSF);
    float4 wqv = *(const float4*)(wq + c4);
    float4 qn = make_float4(qv.x * qinv * wqv.x, qv.y * qinv * wqv.y,
                            qv.z * qinv * wqv.z, qv.w * qinv * wqv.w);
    float4 wkv = *(const float4*)(wk + c4);

    const int row0 = offsets[node];
    const int row1 = offsets[node + 1];

    float m = -INFINITY;
    float l = 0.0f;
    float4 acc = make_float4(0.f, 0.f, 0.f, 0.f);

    for (int j = row0; j < row1; ++j) {
        int eid = perm_eid[j];
        int src = perm_src[j];
        const size_t e_off = ((size_t)eid * H_DIM + h) * C_DIM + c4;
        const size_t s_off = ((size_t)src * H_DIM + h) * C_DIM + c4;
        float4 ev = *(const float4*)(e + e_off);
        float4 kv = *(const float4*)(k + s_off);
        float4 vv = *(const float4*)(v + s_off);

        // fused k RMSNorm (per gathered edge; redundant compute, free under mem-bound)
        float ks = kv.x * kv.x + kv.y * kv.y + kv.z * kv.z + kv.w * kv.w;
        ks = reduce8(ks);
        float kinv = rsqrtf(ks * (1.0f / C_DIM) + EPSF);
        float4 ke = make_float4(kv.x * kinv * wkv.x + ev.x,
                                kv.y * kinv * wkv.y + ev.y,
                                kv.z * kinv * wkv.z + ev.z,
                                kv.w * kinv * wkv.w + ev.w);

        float d = qn.x * ke.x + qn.y * ke.y + qn.z * ke.z + qn.w * ke.w;
        d = reduce8(d);
        float s = d * qk_scale;

        float mnew = fmaxf(m, s);
        float sc = __expf(m - mnew);   // first iter: exp(-inf) = 0
        float al = __expf(s - mnew);
        l = l * sc + al;
        acc.x = acc.x * sc + al * (vv.x + ev.x);
        acc.y = acc.y * sc + al * (vv.y + ev.y);
        acc.z = acc.z * sc + al * (vv.z + ev.z);
        acc.w = acc.w * sc + al * (vv.w + ev.w);
        m = mnew;
    }

    float invl = (l > 0.0f) ? (1.0f / l) : 0.0f;  // empty rows -> 0 (matches ref)
    *(float4*)(out + node_off) = make_float4(acc.x * invl, acc.y * invl,
                                             acc.z * invl, acc.w * invl);
}

extern "C" void kernel_launch(void* const* d_in, const int* in_sizes, int n_in,
                              void* d_out, int out_size, void* d_ws, size_t ws_size,
                              hipStream_t stream) {
    const float* q  = (const float*)d_in[0];
    const float* k  = (const float*)d_in[1];
    const float* v  = (const float*)d_in[2];
    const float* e  = (const float*)d_in[3];
    const float* wq = (const float*)d_in[4];
    const float* wk = (const float*)d_in[5];
    const int* esrc = (const int*)d_in[6];
    const int* edst = (const int*)d_in[7];
    float* out = (float*)d_out;

    const int NE = in_sizes[6];
    const int C  = in_sizes[4];           // 32
    const int HC = in_sizes[3] / NE;      // H*C
    const int N  = in_sizes[0] / HC;      // 16384
    (void)C;

    // workspace layout (ints): counts[N] | cursor[N] | offsets[N+1] | perm_eid[NE] | perm_src[NE]
    int* wsp      = (int*)d_ws;
    int* counts   = wsp;
    int* cursor   = wsp + N;
    int* offsets  = wsp + 2 * N;
    int* perm_eid = wsp + 3 * N + 1;
    int* perm_src = perm_eid + NE;

    zero_kernel<<<(2 * N + 255) / 256, 256, 0, stream>>>(counts, 2 * N);
    hist_kernel<<<(NE + 255) / 256, 256, 0, stream>>>(edst, counts, NE);
    scan_kernel<<<1, 1024, 0, stream>>>(counts, offsets, N);
    scatter_kernel<<<(NE + 255) / 256, 256, 0, stream>>>(esrc, edst, offsets, cursor,
                                                         perm_eid, perm_src, NE);
    attn_kernel<<<N, 128, 0, stream>>>(q, k, v, e, wq, wk, offsets,
                                       perm_eid, perm_src, out);
}

// Round 2
// 686.079 us; speedup vs baseline: 1.0239x; 1.0239x over previous
//
#include <hip/hip_runtime.h>
#include <math.h>

// Problem constants (fixed by the reference: N=16384, H=16, C=32, NE=196608)
#define H_DIM 16
#define C_DIM 32
#define HC_DIM (H_DIM * C_DIM)   // 512
#define EPSF 1e-5f

__device__ __forceinline__ float reduce8(float x) {
    // sum across the 8 lanes that share one head; lanes are contiguous within
    // a 64-lane wave, so xor masks 1/2/4 never cross the wave boundary.
    x += __shfl_xor(x, 1);
    x += __shfl_xor(x, 2);
    x += __shfl_xor(x, 4);
    return x;
}

__global__ void zero_kernel(int* __restrict__ p, int n) {
    int i = blockIdx.x * blockDim.x + threadIdx.x;
    if (i < n) p[i] = 0;
}

__global__ void hist_kernel(const int* __restrict__ edst, int* __restrict__ counts, int ne) {
    int i = blockIdx.x * blockDim.x + threadIdx.x;
    if (i < ne) atomicAdd(&counts[edst[i]], 1);
}

// Single-block exclusive scan over counts[n] -> offsets[n+1].
// Wave-level shuffle scan: 3 barriers per 1024-chunk (vs 20 in the log-LDS
// version, which was barrier-bound on one CU).
__global__ __launch_bounds__(1024)
void scan_kernel(const int* __restrict__ counts, int* __restrict__ offsets, int n) {
    __shared__ int wsum[16];
    __shared__ int carry_s;
    const int tid = threadIdx.x;
    const int lane = tid & 63;
    const int wid = tid >> 6;
    if (tid == 0) { carry_s = 0; offsets[0] = 0; }
    __syncthreads();
    for (int base = 0; base < n; base += 1024) {
        int x = (base + tid < n) ? counts[base + tid] : 0;
        // inclusive scan within the wave
        int v = x;
        #pragma unroll
        for (int off = 1; off < 64; off <<= 1) {
            int y = __shfl_up(v, off);
            if (lane >= off) v += y;
        }
        if (lane == 63) wsum[wid] = v;
        __syncthreads();
        if (wid == 0 && lane < 16) {
            int s = wsum[lane];
            #pragma unroll
            for (int off = 1; off < 16; off <<= 1) {
                int y = __shfl_up(s, off);
                if (lane >= off) s += y;
            }
            wsum[lane] = s;  // inclusive scan of wave sums
        }
        __syncthreads();
        int waveoff = (wid == 0) ? 0 : wsum[wid - 1];
        int carry = carry_s;
        if (base + tid < n) offsets[base + tid + 1] = carry + waveoff + v;
        __syncthreads();  // everyone has read carry_s / wsum
        if (tid == 1023) carry_s = carry + wsum[15];
        __syncthreads();
    }
}

__global__ void scatter_kernel(const int* __restrict__ esrc, const int* __restrict__ edst,
                               const int* __restrict__ offsets, int* __restrict__ cursor,
                               int2* __restrict__ perm, int ne) {
    int i = blockIdx.x * blockDim.x + threadIdx.x;
    if (i < ne) {
        int d = edst[i];
        int pos = offsets[d] + atomicAdd(&cursor[d], 1);
        perm[pos] = make_int2(esrc[i], i);  // {src, eid}
    }
}

// Online-softmax update given already-loaded edge data.
__device__ __forceinline__ void update_edge(float4 ev, float4 kv, float4 vv,
                                            float4 qn, float4 wkv, float qk_scale,
                                            float& m, float& l, float4& acc) {
    float ks = kv.x * kv.x + kv.y * kv.y + kv.z * kv.z + kv.w * kv.w;
    ks = reduce8(ks);
    float kinv = rsqrtf(ks * (1.0f / C_DIM) + EPSF);
    float kex = kv.x * kinv * wkv.x + ev.x;
    float key = kv.y * kinv * wkv.y + ev.y;
    float kez = kv.z * kinv * wkv.z + ev.z;
    float kew = kv.w * kinv * wkv.w + ev.w;
    float d = qn.x * kex + qn.y * key + qn.z * kez + qn.w * kew;
    d = reduce8(d);
    float s = d * qk_scale;
    float mnew = fmaxf(m, s);
    float sc = __expf(m - mnew);   // first edge: exp(-inf) = 0
    float al = __expf(s - mnew);
    l = l * sc + al;
    acc.x = acc.x * sc + al * (vv.x + ev.x);
    acc.y = acc.y * sc + al * (vv.y + ev.y);
    acc.z = acc.z * sc + al * (vv.z + ev.z);
    acc.w = acc.w * sc + al * (vv.w + ev.w);
    m = mnew;
}

// One block per dst node. 128 threads = 16 heads x 8 lanes; each lane owns a
// float4 of the C=32 channel dim (channel offset within a node = 4*threadIdx).
// Edges split into two independent online-softmax streams (merged at the end)
// to double loads-in-flight per wave.
__global__ __launch_bounds__(128)
void attn_kernel(const float* __restrict__ q, const float* __restrict__ k,
                 const float* __restrict__ v, const float* __restrict__ e,
                 const float* __restrict__ wq, const float* __restrict__ wk,
                 const int* __restrict__ offsets, const int2* __restrict__ perm,
                 float* __restrict__ out)
{
    const int node = blockIdx.x;
    const int t = threadIdx.x;
    const int hc = t << 2;             // h*C + c4 == 4*t
    const int c4 = (t & 7) << 2;
    const float qk_scale = 0.17677669529663687f;  // 1/sqrt(32)

    const int node_off = node * HC_DIM + hc;

    // fused q RMSNorm (once per node)
    float4 qv = *(const float4*)(q + node_off);
    float qs = qv.x * qv.x + qv.y * qv.y + qv.z * qv.z + qv.w * qv.w;
    qs = reduce8(qs);
    float qinv = rsqrtf(qs * (1.0f / C_DIM) + EPSF);
    float4 wqv = *(const float4*)(wq + c4);
    float4 qn = make_float4(qv.x * qinv * wqv.x, qv.y * qinv * wqv.y,
                            qv.z * qinv * wqv.z, qv.w * qinv * wqv.w);
    float4 wkv = *(const float4*)(wk + c4);

    const int row0 = offsets[node];
    const int row1 = offsets[node + 1];
    const int len = row1 - row0;
    const int mid = row0 + ((len + 1) >> 1);

    float mA = -INFINITY, lA = 0.0f, mB = -INFINITY, lB = 0.0f;
    float4 accA = make_float4(0.f, 0.f, 0.f, 0.f);
    float4 accB = make_float4(0.f, 0.f, 0.f, 0.f);

    int jA = row0, jB = mid;
    while (jA < mid && jB < row1) {
        int2 pA = perm[jA];
        int2 pB = perm[jB];
        // issue all six gathers before any compute
        const float4 evA = *(const float4*)(e + (size_t)pA.y * HC_DIM + hc);
        const float4 kvA = *(const float4*)(k + pA.x * HC_DIM + hc);
        const float4 vvA = *(const float4*)(v + pA.x * HC_DIM + hc);
        const float4 evB = *(const float4*)(e + (size_t)pB.y * HC_DIM + hc);
        const float4 kvB = *(const float4*)(k + pB.x * HC_DIM + hc);
        const float4 vvB = *(const float4*)(v + pB.x * HC_DIM + hc);
        update_edge(evA, kvA, vvA, qn, wkv, qk_scale, mA, lA, accA);
        update_edge(evB, kvB, vvB, qn, wkv, qk_scale, mB, lB, accB);
        ++jA; ++jB;
    }
    while (jA < mid) {   // at most one extra iteration (lenA = lenB or lenB+1)
        int2 p = perm[jA];
        const float4 ev = *(const float4*)(e + (size_t)p.y * HC_DIM + hc);
        const float4 kv = *(const float4*)(k + p.x * HC_DIM + hc);
        const float4 vv = *(const float4*)(v + p.x * HC_DIM + hc);
        update_edge(ev, kv, vv, qn, wkv, qk_scale, mA, lA, accA);
        ++jA;
    }

    // merge the two streams (guard exp(-inf - -inf) = NaN for empty streams)
    float M = fmaxf(mA, mB);
    float fA = (lA > 0.0f) ? __expf(mA - M) : 0.0f;
    float fB = (lB > 0.0f) ? __expf(mB - M) : 0.0f;
    float l = lA * fA + lB * fB;
    float4 acc = make_float4(accA.x * fA + accB.x * fB,
                             accA.y * fA + accB.y * fB,
                             accA.z * fA + accB.z * fB,
                             accA.w * fA + accB.w * fB);

    float invl = (l > 0.0f) ? (1.0f / l) : 0.0f;  // empty rows -> 0 (matches ref)
    *(float4*)(out + node_off) = make_float4(acc.x * invl, acc.y * invl,
                                             acc.z * invl, acc.w * invl);
}

extern "C" void kernel_launch(void* const* d_in, const int* in_sizes, int n_in,
                              void* d_out, int out_size, void* d_ws, size_t ws_size,
                              hipStream_t stream) {
    const float* q  = (const float*)d_in[0];
    const float* k  = (const float*)d_in[1];
    const float* v  = (const float*)d_in[2];
    const float* e  = (const float*)d_in[3];
    const float* wq = (const float*)d_in[4];
    const float* wk = (const float*)d_in[5];
    const int* esrc = (const int*)d_in[6];
    const int* edst = (const int*)d_in[7];
    float* out = (float*)d_out;

    const int NE = in_sizes[6];
    const int HC = in_sizes[3] / NE;      // H*C
    const int N  = in_sizes[0] / HC;      // 16384

    // workspace layout: perm[NE] (int2, 8B-aligned first) | counts[N] | cursor[N] | offsets[N+1]
    int2* perm    = (int2*)d_ws;
    int* counts   = (int*)(perm + NE);
    int* cursor   = counts + N;
    int* offsets  = cursor + N;

    zero_kernel<<<(2 * N + 255) / 256, 256, 0, stream>>>(counts, 2 * N);
    hist_kernel<<<(NE + 255) / 256, 256, 0, stream>>>(edst, counts, NE);
    scan_kernel<<<1, 1024, 0, stream>>>(counts, offsets, N);
    scatter_kernel<<<(NE + 255) / 256, 256, 0, stream>>>(esrc, edst, offsets, cursor,
                                                         perm, NE);
    attn_kernel<<<N, 128, 0, stream>>>(q, k, v, e, wq, wk, offsets, perm, out);
}